// Round 12
// baseline (119.131 us; speedup 1.0000x reference)
//
#include <hip/hip_runtime.h>

// TopicRouter: logits = h @ gate_w^T + gate_b ; top-2 ; softmax over top-2.
// Outputs flat in d_out (float32): [0, 2B)   = topk idx as floats
//                                  [2B, 4B)  = softmax weights
//
// R12 = R11 (wave-per-token + LDS-slot prefetch) with the two R11 bugs fixed:
//  BUG1: lane-0 output stores increment vmcnt too -> vmcnt(6) over-drained,
//        collapsing prefetch depth to ~1. FIX: count them. Steady wait =
//        vmcnt(15) = 6 younger DMAs + 9 younger stores (order [DMA,stores]
//        pinned per iteration). Ramp: k=0,1,2 -> vmcnt(6); tail -> vmcnt(9).
//  BUG2: ds_read -> lgkmcnt(0) -> DMA stalled ~120cyc before FMAs each token.
//        FIX: reissue AFTER the FMA block (reads consumed -> lgkm already
//        drained -> fence is free).
//  Also: bias forced to SGPR via readfirstlane (-8 VGPR). Est ~125 VGPR,
//  36 KB LDS -> 4 blocks/CU x 4 waves = 4 waves/SIMD.
// Unchanged from R9: wave-per-token, wf in 96 VGPRs, f32 dot + 18-op
// split-butterfly + top-3; flag + separate f64 repair kernel (one top-2
// rank flip vs the f64 np ref fails the 0.14 idx threshold; f32 path error
// ~1e-6 vs TAU=1e-4 margin; ~1e-3 trigger rate).

#define B_TOKENS 131072
#define DM 768
#define NE 8
#define TAU 1e-4f
#define NWAVES 4096         // 1024 blocks x 4 waves
#define NT 32               // tokens per wave = 131072 / 4096 (exact)

typedef const __attribute__((address_space(1))) void* gbl_vp;
typedef __attribute__((address_space(3))) void* lds_vp;

__device__ __forceinline__ void dma16(const float* g, float* l) {
    __builtin_amdgcn_global_load_lds((gbl_vp)g, (lds_vp)l, 16, 0, 0);
}

__global__ __launch_bounds__(256) void router_main(
    const float* __restrict__ h,     // [B, 768]
    const float* __restrict__ gw,    // [8, 768]
    const float* __restrict__ gb,    // [8]
    float* __restrict__ out,         // [2B idx floats][2B weight floats]
    unsigned char* __restrict__ flags)
{
    __shared__ __align__(16) float hslots[4][3][DM];   // 36 KB, wave-private

    const int tid  = threadIdx.x;
    const int lane = tid & 63;
    const int wv   = __builtin_amdgcn_readfirstlane(tid >> 6);
    const int wid  = blockIdx.x * 4 + (tid >> 6);      // [0, 4096)

    // ---- weight cache in VGPRs: wf[e][g] = gw[e][g*256 + lane*4 .. +3] ----
    float4 wf[NE][3];
#pragma unroll
    for (int e = 0; e < NE; ++e)
#pragma unroll
        for (int g = 0; g < 3; ++g)
            wf[e][g] = *reinterpret_cast<const float4*>(
                &gw[e * DM + g * 256 + lane * 4]);

    float biasf[NE];   // force into SGPRs (wave-uniform)
#pragma unroll
    for (int e = 0; e < NE; ++e)
        biasf[e] = __uint_as_float(
            __builtin_amdgcn_readfirstlane(__float_as_uint(gb[e])));

    // ---- DMA prologue: tokens 0,1,2 into slots 0,1,2 (9 DMAs in flight) ----
#pragma unroll
    for (int kk = 0; kk < 3; ++kk) {
        const float* row = h + (size_t)(wid + kk * NWAVES) * DM;
#pragma unroll
        for (int i = 0; i < 3; ++i)
            dma16(row + i * 256 + lane * 4, &hslots[wv][kk][i * 256]);
    }

    const bool hi32 = (lane & 32) != 0;
    const bool hi16 = (lane & 16) != 0;
    const bool hi8  = (lane & 8)  != 0;

    for (int k = 0; k < NT; ++k) {
        const int t = wid + k * NWAVES;

        // ---- counted wait; stores ARE counted (3 per past iteration) ----
        // younger-op count after token k's DMAs:
        //   k=0:6  k=1:9(use 6)  k=2:12(use 6)  3<=k<=NT-3:15  tail: >=9
        if (k < 3)            asm volatile("s_waitcnt vmcnt(6)"  ::: "memory");
        else if (k >= NT - 2) asm volatile("s_waitcnt vmcnt(9)"  ::: "memory");
        else                  asm volatile("s_waitcnt vmcnt(15)" ::: "memory");

        // ---- read this token's 12 dims from its slot (3x ds_read_b128) ----
        const float* slot = &hslots[wv][k % 3][0];
        const float4 h0 = *reinterpret_cast<const float4*>(&slot[0 + lane * 4]);
        const float4 h1 = *reinterpret_cast<const float4*>(&slot[256 + lane * 4]);
        const float4 h2 = *reinterpret_cast<const float4*>(&slot[512 + lane * 4]);

        // ---- f32 partial dot: 96 FMAs/lane (forces lgkm drain of reads) ----
        float accf[NE] = {0, 0, 0, 0, 0, 0, 0, 0};
#pragma unroll
        for (int e = 0; e < NE; ++e) {
            accf[e] = fmaf(h0.x, wf[e][0].x, accf[e]);
            accf[e] = fmaf(h0.y, wf[e][0].y, accf[e]);
            accf[e] = fmaf(h0.z, wf[e][0].z, accf[e]);
            accf[e] = fmaf(h0.w, wf[e][0].w, accf[e]);
            accf[e] = fmaf(h1.x, wf[e][1].x, accf[e]);
            accf[e] = fmaf(h1.y, wf[e][1].y, accf[e]);
            accf[e] = fmaf(h1.z, wf[e][1].z, accf[e]);
            accf[e] = fmaf(h1.w, wf[e][1].w, accf[e]);
            accf[e] = fmaf(h2.x, wf[e][2].x, accf[e]);
            accf[e] = fmaf(h2.y, wf[e][2].y, accf[e]);
            accf[e] = fmaf(h2.z, wf[e][2].z, accf[e]);
            accf[e] = fmaf(h2.w, wf[e][2].w, accf[e]);
        }

        // ---- reissue token k+3 into the slot just consumed ----
        __builtin_amdgcn_sched_barrier(0);
        asm volatile("s_waitcnt lgkmcnt(0)" ::: "memory");  // free: reads consumed
        if (k + 3 < NT) {
            const float* row = h + (size_t)(t + 3 * NWAVES) * DM;
            float* dst = &hslots[wv][k % 3][0];
#pragma unroll
            for (int i = 0; i < 3; ++i)
                dma16(row + i * 256 + lane * 4, dst + i * 256);
        }
        __builtin_amdgcn_sched_barrier(0);

        // ---- f32 split-butterfly reduce (18 b32 DS ops) ----
        float r4[4];
#pragma unroll
        for (int j = 0; j < 4; ++j) {
            const float give = hi32 ? accf[j] : accf[4 + j];
            const float keep = hi32 ? accf[4 + j] : accf[j];
            r4[j] = keep + __shfl_xor(give, 32);
        }
        float r2[2];
#pragma unroll
        for (int j = 0; j < 2; ++j) {
            const float give = hi16 ? r4[j] : r4[2 + j];
            const float keep = hi16 ? r4[2 + j] : r4[j];
            r2[j] = keep + __shfl_xor(give, 16);
        }
        const float give = hi8 ? r2[0] : r2[1];
        const float keep = hi8 ? r2[1] : r2[0];
        float v = keep + __shfl_xor(give, 8);
        v += __shfl_xor(v, 4);
        v += __shfl_xor(v, 2);
        v += __shfl_xor(v, 1);

        // gather all 8 logits into every lane (identical across lanes)
        float lg[NE];
#pragma unroll
        for (int e = 0; e < NE; ++e)
            lg[e] = __shfl(v, (e << 3) | (lane & 7)) + biasf[e];

        // ---- f32 top-3 (lax.top_k tie-break: lower index wins) ----
        int i0 = 0; float v0 = lg[0];
#pragma unroll
        for (int e = 1; e < NE; ++e)
            if (lg[e] > v0) { v0 = lg[e]; i0 = e; }
        int i1 = -1; float v1 = -3.4e38f;
#pragma unroll
        for (int e = 0; e < NE; ++e)
            if (e != i0 && lg[e] > v1) { v1 = lg[e]; i1 = e; }
        float v2 = -3.4e38f;
#pragma unroll
        for (int e = 0; e < NE; ++e)
            if (e != i0 && e != i1 && lg[e] > v2) v2 = lg[e];

        const bool amb = (v0 - v1 < TAU) || (v1 - v2 < TAU);

        const float ex = expf(v1 - v0);    // <= 1
        const float w1 = ex / (1.0f + ex);
        const float w0 = 1.0f - w1;

        // ---- stores LAST (3 VMEM instrs; order [DMA, stores] pinned) ----
        if (lane == 0) {
            *reinterpret_cast<float2*>(&out[2 * (size_t)t]) =
                make_float2((float)i0, (float)i1);
            *reinterpret_cast<float2*>(
                &out[2 * (size_t)B_TOKENS + 2 * (size_t)t]) =
                make_float2(w0, w1);
            flags[t] = amb ? 1 : 0;        // always written -> deterministic
        }
    }
}

// One wave per 64 consecutive tokens; early-exit when no flags set. (R9-proven.)
__global__ __launch_bounds__(256) void router_repair(
    const float* __restrict__ h,
    const float* __restrict__ gw,
    const float* __restrict__ gb,
    float* __restrict__ out,
    const unsigned char* __restrict__ flags)
{
    const int lane = threadIdx.x & 63;
    const int w = (blockIdx.x * blockDim.x + threadIdx.x) >> 6;
    const int t0 = w * 64;
    if (t0 >= B_TOKENS) return;

    const unsigned char f = flags[t0 + lane];
    unsigned long long mask = __ballot(f != 0);
    if (mask == 0ull) return;

    float wf[NE][3][4];
#pragma unroll
    for (int e = 0; e < NE; ++e)
#pragma unroll
        for (int g = 0; g < 3; ++g) {
            const float4 vv = *reinterpret_cast<const float4*>(
                &gw[e * DM + g * 256 + lane * 4]);
            wf[e][g][0] = vv.x; wf[e][g][1] = vv.y;
            wf[e][g][2] = vv.z; wf[e][g][3] = vv.w;
        }
    double biasd[NE];
#pragma unroll
    for (int e = 0; e < NE; ++e) biasd[e] = (double)gb[e];

    const bool hi32 = (lane & 32) != 0;
    const bool hi16 = (lane & 16) != 0;
    const bool hi8  = (lane & 8)  != 0;

    while (mask) {
        const int p = __ffsll(mask) - 1;
        mask &= (mask - 1);
        const int t = t0 + p;

        const float* hr = h + (size_t)t * DM;
        float4 buf[3];
#pragma unroll
        for (int g = 0; g < 3; ++g)
            buf[g] = *reinterpret_cast<const float4*>(&hr[g * 256 + lane * 4]);

        double acc[NE] = {0, 0, 0, 0, 0, 0, 0, 0};
#pragma unroll
        for (int g = 0; g < 3; ++g) {
            const float* bp = reinterpret_cast<const float*>(&buf[g]);
#pragma unroll
            for (int j = 0; j < 4; ++j) {
                const double hd = (double)bp[j];
#pragma unroll
                for (int e = 0; e < NE; ++e)
                    acc[e] = fma(hd, (double)wf[e][g][j], acc[e]);
            }
        }
        double d4[4];
#pragma unroll
        for (int j = 0; j < 4; ++j) {
            const double give = hi32 ? acc[j] : acc[4 + j];
            const double keep = hi32 ? acc[4 + j] : acc[j];
            d4[j] = keep + __shfl_xor(give, 32);
        }
        double d2[2];
#pragma unroll
        for (int j = 0; j < 2; ++j) {
            const double give = hi16 ? d4[j] : d4[2 + j];
            const double keep = hi16 ? d4[2 + j] : d4[j];
            d2[j] = keep + __shfl_xor(give, 16);
        }
        const double give = hi8 ? d2[0] : d2[1];
        const double keep = hi8 ? d2[1] : d2[0];
        double dv = keep + __shfl_xor(give, 8);
        dv += __shfl_xor(dv, 4);
        dv += __shfl_xor(dv, 2);
        dv += __shfl_xor(dv, 1);

        double dlg[NE];
#pragma unroll
        for (int e = 0; e < NE; ++e)
            dlg[e] = __shfl(dv, (e << 3) | (lane & 7)) + biasd[e];

        int i0 = 0; double dv0 = dlg[0];
#pragma unroll
        for (int e = 1; e < NE; ++e)
            if (dlg[e] > dv0) { dv0 = dlg[e]; i0 = e; }
        int i1 = (i0 == 0) ? 1 : 0; double dv1 = dlg[i1];
#pragma unroll
        for (int e = 0; e < NE; ++e)
            if (e != i0 && dlg[e] > dv1) { dv1 = dlg[e]; i1 = e; }

        const float ex = expf((float)(dv1 - dv0));
        const float w1 = ex / (1.0f + ex);
        const float w0 = 1.0f - w1;

        if (lane == 0) {
            *reinterpret_cast<float2*>(&out[2 * (size_t)t]) =
                make_float2((float)i0, (float)i1);
            *reinterpret_cast<float2*>(
                &out[2 * (size_t)B_TOKENS + 2 * (size_t)t]) =
                make_float2(w0, w1);
        }
    }
}

extern "C" void kernel_launch(void* const* d_in, const int* in_sizes, int n_in,
                              void* d_out, int out_size, void* d_ws, size_t ws_size,
                              hipStream_t stream) {
    const float* h  = (const float*)d_in[0];
    const float* gw = (const float*)d_in[1];
    const float* gb = (const float*)d_in[2];
    float* out = (float*)d_out;
    unsigned char* flags = (unsigned char*)d_ws;   // B_TOKENS bytes

    router_main<<<dim3(1024), dim3(256), 0, stream>>>(h, gw, gb, out, flags);
    router_repair<<<dim3(512), dim3(256), 0, stream>>>(h, gw, gb, out, flags);
}

// Round 13
// 88.888 us; speedup vs baseline: 1.3402x; 1.3402x over previous
//
#include <hip/hip_runtime.h>
#include <hip/hip_bf16.h>

// TopicRouter: logits = h @ gate_w^T + gate_b ; top-2 ; softmax over top-2.
// Outputs flat in d_out (float32): [0, 2B)   = topk idx as floats
//                                  [2B, 4B)  = softmax weights
//
// R13 — MFMA gate projection (structural pivot):
//  * R7..R12 all orbit 104-122 us: wave-per-token pays a 96-VGPR weight
//    cache (3-4 waves/SIMD) + ~26 DS ops/token of dependent shuffle chain.
//  * Here the [B,768]x[768,8] projection runs on the matrix pipe:
//    mfma_f32_16x16x32_bf16, hi/lo split 3-product trick
//    (hi*hi + hi*lo + lo*hi -> one f32 acc). bf16xbf16 is exact in f32;
//    error = dropped lo*lo ~ 2e-5 worst case << TAU=2.5e-4 -> the R9-proven
//    flag + f64 repair kernel guarantees exact top-2 ranking.
//  * A (h rows) read straight from global: lane holds row (lane&15),
//    k-grp (lane>>4) -> 16 full 128B lines per instr pair. No h staging.
//  * B (w hi/lo) in LDS, built once per block: [kstep][col][hi32|lo32]
//    col stride 144B (16B-aligned, <=4-way b128 conflict). Cols 8..15
//    read a zero stub (bias -inf masks them in the epilogue).
//  * Epilogue per C-reg: top-3 merge butterfly over xor 1/2/4 (cols ARE
//    lanes) + 2 ballots for argmax with exact lax.top_k tie-break
//    (lower index wins). ~3 DS ops/token vs 26 in R9.
//  * A/B k-group mapping is self-consistent (any k-permutation applied to
//    both A and B leaves C unchanged); row/col mapping is the m89-verified
//    C layout: col = lane&15, row = (lane>>4)*4 + reg.

#define B_TOKENS 131072
#define DM 768
#define NE 8
#define TAU 2.5e-4f
#define NEG_BIG -3.0e38f

typedef __attribute__((ext_vector_type(8))) short bf16x8;
typedef __attribute__((ext_vector_type(4))) float f32x4;

__device__ __forceinline__ unsigned short f32_to_bf16(float f) {
    __hip_bfloat16 b = __float2bfloat16(f);
    return *reinterpret_cast<unsigned short*>(&b);
}
__device__ __forceinline__ float bf16_to_f32(unsigned short u) {
    return __uint_as_float((unsigned)u << 16);
}

__global__ __launch_bounds__(256) void router_main(
    const float* __restrict__ h,     // [B, 768]
    const float* __restrict__ gw,    // [8, 768]
    const float* __restrict__ gb,    // [8]
    float* __restrict__ out,         // [2B idx floats][2B weight floats]
    unsigned char* __restrict__ flags)
{
    // [kstep 24][col 8: 72 ushorts = 32 hi + 32 lo + 8 pad] + 8 zero stub
    __shared__ __align__(16) unsigned short w_lds[24 * 576 + 8];

    const int tid  = threadIdx.x;
    const int lane = tid & 63;
    const int wv   = tid >> 6;
    const int col  = lane & 15;
    const int kg   = lane >> 4;

    // ---- build B hi/lo in LDS (once per block) ----
    for (int idx = tid; idx < NE * DM; idx += 256) {
        const int e = idx / DM, k = idx - e * DM;
        const float w = gw[idx];
        const unsigned short hb = f32_to_bf16(w);
        const unsigned short lb = f32_to_bf16(w - bf16_to_f32(hb));
        const int ks = k >> 5, kk = k & 31;
        w_lds[ks * 576 + e * 72 + kk]      = hb;
        w_lds[ks * 576 + e * 72 + 32 + kk] = lb;
    }
    if (tid < 8) w_lds[24 * 576 + tid] = 0;

    const float bias_lane = (col < 8) ? gb[col] : NEG_BIG;
    __syncthreads();

    // ---- per-wave 16-token tile ----
    const int tile = blockIdx.x * 4 + wv;            // [0, 8192)
    const float* arow = h + (size_t)(tile * 16 + col) * DM + kg * 8;

    const unsigned short* bptr =
        (col < 8) ? &w_lds[col * 72 + kg * 8] : &w_lds[24 * 576];
    const int bstep = (col < 8) ? 576 : 0;
    const int bloff = (col < 8) ? 32 : 0;

    f32x4 acc = {0.f, 0.f, 0.f, 0.f};
#pragma unroll 4
    for (int ks = 0; ks < 24; ++ks) {
        const float4 p = *reinterpret_cast<const float4*>(arow + ks * 32);
        const float4 q = *reinterpret_cast<const float4*>(arow + ks * 32 + 4);
        bf16x8 ahi, alo;
        {
            const float fv[8] = {p.x, p.y, p.z, p.w, q.x, q.y, q.z, q.w};
#pragma unroll
            for (int j = 0; j < 8; ++j) {
                const unsigned short hb = f32_to_bf16(fv[j]);
                const unsigned short lb = f32_to_bf16(fv[j] - bf16_to_f32(hb));
                ahi[j] = (short)hb;
                alo[j] = (short)lb;
            }
        }
        const bf16x8 bhi = *reinterpret_cast<const bf16x8*>(bptr + ks * bstep);
        const bf16x8 blo = *reinterpret_cast<const bf16x8*>(bptr + ks * bstep + bloff);
        acc = __builtin_amdgcn_mfma_f32_16x16x32_bf16(ahi, bhi, acc, 0, 0, 0);
        acc = __builtin_amdgcn_mfma_f32_16x16x32_bf16(ahi, blo, acc, 0, 0, 0);
        acc = __builtin_amdgcn_mfma_f32_16x16x32_bf16(alo, bhi, acc, 0, 0, 0);
    }

    // ---- epilogue: per C-reg (row = (lane>>4)*4 + i), top-3 + argmax ----
    const unsigned gsh = (unsigned)(lane & 48);
#pragma unroll
    for (int i = 0; i < 4; ++i) {
        const float lg = acc[i] + bias_lane;    // cols>=8: 0 + (-3e38)
        float a0 = lg, a1 = NEG_BIG, a2 = NEG_BIG;
#pragma unroll
        for (int m = 1; m <= 4; m <<= 1) {
            const float b0 = __shfl_xor(a0, m);
            const float b1 = __shfl_xor(a1, m);
            const float b2 = __shfl_xor(a2, m);
            const float x  = fminf(a0, b0);
            const float c0 = fmaxf(a0, b0);
            const float y  = fmaxf(a1, b1);
            const float z  = fminf(a1, b1);
            const float c1 = fmaxf(x, y);
            const float c2 = fmaxf(fminf(x, y), fmaxf(z, fmaxf(a2, b2)));
            a0 = c0; a1 = c1; a2 = c2;
        }
        // argmax via ballot; exact lax.top_k tie-break (lower index wins)
        const unsigned long long m0 = __ballot(lg == a0);
        const unsigned long long m1 = __ballot(lg == a1);
        const unsigned mk0 = (unsigned)(m0 >> gsh) & 0xFFu;
        const unsigned mk1 = (unsigned)(m1 >> gsh) & 0xFFu;
        const int i0 = __builtin_ctz(mk0);
        const unsigned rest = mk0 & (mk0 - 1);
        const int i1 = (a1 == a0) ? __builtin_ctz(rest | 0x100u)
                                  : __builtin_ctz(mk1 | 0x100u);

        const bool amb = (a0 - a1 < TAU) || (a1 - a2 < TAU);
        const float ex = expf(a1 - a0);        // <= 1
        const float w1 = ex / (1.f + ex);
        const float w0 = 1.f - w1;

        if (col == 0) {
            const size_t t = (size_t)(tile * 16 + (lane >> 4) * 4 + i);
            *reinterpret_cast<float2*>(&out[2 * t]) =
                make_float2((float)i0, (float)i1);
            *reinterpret_cast<float2*>(&out[2 * (size_t)B_TOKENS + 2 * t]) =
                make_float2(w0, w1);
            flags[t] = amb ? 1 : 0;            // always written
        }
    }
}

// One wave per 64 consecutive tokens; early-exit when no flags set. (R9-proven.)
__global__ __launch_bounds__(256) void router_repair(
    const float* __restrict__ h,
    const float* __restrict__ gw,
    const float* __restrict__ gb,
    float* __restrict__ out,
    const unsigned char* __restrict__ flags)
{
    const int lane = threadIdx.x & 63;
    const int w = (blockIdx.x * blockDim.x + threadIdx.x) >> 6;
    const int t0 = w * 64;
    if (t0 >= B_TOKENS) return;

    const unsigned char f = flags[t0 + lane];
    unsigned long long mask = __ballot(f != 0);
    if (mask == 0ull) return;

    float wf[NE][3][4];
#pragma unroll
    for (int e = 0; e < NE; ++e)
#pragma unroll
        for (int g = 0; g < 3; ++g) {
            const float4 vv = *reinterpret_cast<const float4*>(
                &gw[e * DM + g * 256 + lane * 4]);
            wf[e][g][0] = vv.x; wf[e][g][1] = vv.y;
            wf[e][g][2] = vv.z; wf[e][g][3] = vv.w;
        }
    double biasd[NE];
#pragma unroll
    for (int e = 0; e < NE; ++e) biasd[e] = (double)gb[e];

    const bool hi32 = (lane & 32) != 0;
    const bool hi16 = (lane & 16) != 0;
    const bool hi8  = (lane & 8)  != 0;

    while (mask) {
        const int p = __ffsll((unsigned long long)mask) - 1;
        mask &= (mask - 1);
        const int t = t0 + p;

        const float* hr = h + (size_t)t * DM;
        float4 buf[3];
#pragma unroll
        for (int g = 0; g < 3; ++g)
            buf[g] = *reinterpret_cast<const float4*>(&hr[g * 256 + lane * 4]);

        double acc[NE] = {0, 0, 0, 0, 0, 0, 0, 0};
#pragma unroll
        for (int g = 0; g < 3; ++g) {
            const float* bp = reinterpret_cast<const float*>(&buf[g]);
#pragma unroll
            for (int j = 0; j < 4; ++j) {
                const double hd = (double)bp[j];
#pragma unroll
                for (int e = 0; e < NE; ++e)
                    acc[e] = fma(hd, (double)wf[e][g][j], acc[e]);
            }
        }
        double d4[4];
#pragma unroll
        for (int j = 0; j < 4; ++j) {
            const double give = hi32 ? acc[j] : acc[4 + j];
            const double keep = hi32 ? acc[4 + j] : acc[j];
            d4[j] = keep + __shfl_xor(give, 32);
        }
        double d2[2];
#pragma unroll
        for (int j = 0; j < 2; ++j) {
            const double give = hi16 ? d4[j] : d4[2 + j];
            const double keep = hi16 ? d4[2 + j] : d4[j];
            d2[j] = keep + __shfl_xor(give, 16);
        }
        const double give = hi8 ? d2[0] : d2[1];
        const double keep = hi8 ? d2[1] : d2[0];
        double dv = keep + __shfl_xor(give, 8);
        dv += __shfl_xor(dv, 4);
        dv += __shfl_xor(dv, 2);
        dv += __shfl_xor(dv, 1);

        double dlg[NE];
#pragma unroll
        for (int e = 0; e < NE; ++e)
            dlg[e] = __shfl(dv, (e << 3) | (lane & 7)) + biasd[e];

        int i0 = 0; double dv0 = dlg[0];
#pragma unroll
        for (int e = 1; e < NE; ++e)
            if (dlg[e] > dv0) { dv0 = dlg[e]; i0 = e; }
        int i1 = (i0 == 0) ? 1 : 0; double dv1 = dlg[i1];
#pragma unroll
        for (int e = 0; e < NE; ++e)
            if (e != i0 && dlg[e] > dv1) { dv1 = dlg[e]; i1 = e; }

        const float ex = expf((float)(dv1 - dv0));
        const float w1 = ex / (1.0f + ex);
        const float w0 = 1.0f - w1;

        if (lane == 0) {
            *reinterpret_cast<float2*>(&out[2 * (size_t)t]) =
                make_float2((float)i0, (float)i1);
            *reinterpret_cast<float2*>(
                &out[2 * (size_t)B_TOKENS + 2 * (size_t)t]) =
                make_float2(w0, w1);
        }
    }
}

extern "C" void kernel_launch(void* const* d_in, const int* in_sizes, int n_in,
                              void* d_out, int out_size, void* d_ws, size_t ws_size,
                              hipStream_t stream) {
    const float* h  = (const float*)d_in[0];
    const float* gw = (const float*)d_in[1];
    const float* gb = (const float*)d_in[2];
    float* out = (float*)d_out;
    unsigned char* flags = (unsigned char*)d_ws;   // B_TOKENS bytes

    router_main<<<dim3(2048), dim3(256), 0, stream>>>(h, gw, gb, out, flags);
    router_repair<<<dim3(512), dim3(256), 0, stream>>>(h, gw, gb, out, flags);
}

// Round 14
// 87.019 us; speedup vs baseline: 1.3690x; 1.0215x over previous
//
#include <hip/hip_runtime.h>
#include <hip/hip_bf16.h>

// TopicRouter: logits = h @ gate_w^T + gate_b ; top-2 ; softmax over top-2.
// Outputs flat in d_out (float32): [0, 2B)   = topk idx as floats
//                                  [2B, 4B)  = softmax weights
//
// R14 = R13 (MFMA hi/lo 3-product gate; 88.9 us) + TWO TILES PER WAVE:
//  * R13 residual vs the ~65 us floor attributed to exposed load latency
//    (2 loads in flight per k-step per wave). Here each wave owns two
//    adjacent 16-token tiles: 4 independent loads per k-step, and both
//    tiles share one bhi/blo ds_read pair (halves LDS weight traffic).
//  * Math unchanged: mfma_f32_16x16x32_bf16, hi*hi + hi*lo + lo*hi (exact
//    bf16 products in f32; dropped lo*lo ~2e-5 worst case << TAU=2.5e-4).
//    Flag + f64 repair kernel (R9-proven) guarantees exact top-2 ranking
//    (one rank flip vs the f64 np ref fails the 0.14 idx threshold).
//  * C layout (m89-verified): col = lane&15, row = (lane>>4)*4 + reg.
//  * Grid: 1024 blocks x 4 waves x 32 tokens = 131072 exact.

#define B_TOKENS 131072
#define DM 768
#define NE 8
#define TAU 2.5e-4f
#define NEG_BIG -3.0e38f

typedef __attribute__((ext_vector_type(8))) short bf16x8;
typedef __attribute__((ext_vector_type(4))) float f32x4;

__device__ __forceinline__ unsigned short f32_to_bf16(float f) {
    __hip_bfloat16 b = __float2bfloat16(f);
    return *reinterpret_cast<unsigned short*>(&b);
}
__device__ __forceinline__ float bf16_to_f32(unsigned short u) {
    return __uint_as_float((unsigned)u << 16);
}

__global__ __launch_bounds__(256) void router_main(
    const float* __restrict__ h,     // [B, 768]
    const float* __restrict__ gw,    // [8, 768]
    const float* __restrict__ gb,    // [8]
    float* __restrict__ out,         // [2B idx floats][2B weight floats]
    unsigned char* __restrict__ flags)
{
    // [kstep 24][col 8: 72 ushorts = 32 hi + 32 lo + 8 pad] + 8 zero stub
    __shared__ __align__(16) unsigned short w_lds[24 * 576 + 8];

    const int tid  = threadIdx.x;
    const int lane = tid & 63;
    const int wv   = tid >> 6;
    const int col  = lane & 15;
    const int kg   = lane >> 4;

    // ---- build B hi/lo in LDS (once per block) ----
    for (int idx = tid; idx < NE * DM; idx += 256) {
        const int e = idx / DM, k = idx - e * DM;
        const float w = gw[idx];
        const unsigned short hb = f32_to_bf16(w);
        const unsigned short lb = f32_to_bf16(w - bf16_to_f32(hb));
        const int ks = k >> 5, kk = k & 31;
        w_lds[ks * 576 + e * 72 + kk]      = hb;
        w_lds[ks * 576 + e * 72 + 32 + kk] = lb;
    }
    if (tid < 8) w_lds[24 * 576 + tid] = 0;

    const float bias_lane = (col < 8) ? gb[col] : NEG_BIG;
    __syncthreads();

    // ---- per-wave: two adjacent 16-token tiles ----
    const int tile0 = (blockIdx.x * 4 + wv) * 2;     // [0, 8192) step 2
    const float* arow0 = h + (size_t)(tile0 * 16 + col) * DM + kg * 8;
    const float* arow1 = arow0 + (size_t)16 * DM;

    const unsigned short* bptr =
        (col < 8) ? &w_lds[col * 72 + kg * 8] : &w_lds[24 * 576];
    const int bstep = (col < 8) ? 576 : 0;
    const int bloff = (col < 8) ? 32 : 0;

    f32x4 acc0 = {0.f, 0.f, 0.f, 0.f};
    f32x4 acc1 = {0.f, 0.f, 0.f, 0.f};

#pragma unroll 2
    for (int ks = 0; ks < 24; ++ks) {
        // 4 independent loads in flight
        const float4 p0 = *reinterpret_cast<const float4*>(arow0 + ks * 32);
        const float4 q0 = *reinterpret_cast<const float4*>(arow0 + ks * 32 + 4);
        const float4 p1 = *reinterpret_cast<const float4*>(arow1 + ks * 32);
        const float4 q1 = *reinterpret_cast<const float4*>(arow1 + ks * 32 + 4);

        const bf16x8 bhi = *reinterpret_cast<const bf16x8*>(bptr + ks * bstep);
        const bf16x8 blo = *reinterpret_cast<const bf16x8*>(bptr + ks * bstep + bloff);

        bf16x8 ahi0, alo0, ahi1, alo1;
        {
            const float f0[8] = {p0.x, p0.y, p0.z, p0.w, q0.x, q0.y, q0.z, q0.w};
            const float f1[8] = {p1.x, p1.y, p1.z, p1.w, q1.x, q1.y, q1.z, q1.w};
#pragma unroll
            for (int j = 0; j < 8; ++j) {
                unsigned short hb = f32_to_bf16(f0[j]);
                ahi0[j] = (short)hb;
                alo0[j] = (short)f32_to_bf16(f0[j] - bf16_to_f32(hb));
                hb = f32_to_bf16(f1[j]);
                ahi1[j] = (short)hb;
                alo1[j] = (short)f32_to_bf16(f1[j] - bf16_to_f32(hb));
            }
        }
        acc0 = __builtin_amdgcn_mfma_f32_16x16x32_bf16(ahi0, bhi, acc0, 0, 0, 0);
        acc0 = __builtin_amdgcn_mfma_f32_16x16x32_bf16(ahi0, blo, acc0, 0, 0, 0);
        acc0 = __builtin_amdgcn_mfma_f32_16x16x32_bf16(alo0, bhi, acc0, 0, 0, 0);
        acc1 = __builtin_amdgcn_mfma_f32_16x16x32_bf16(ahi1, bhi, acc1, 0, 0, 0);
        acc1 = __builtin_amdgcn_mfma_f32_16x16x32_bf16(ahi1, blo, acc1, 0, 0, 0);
        acc1 = __builtin_amdgcn_mfma_f32_16x16x32_bf16(alo1, bhi, acc1, 0, 0, 0);
    }

    // ---- epilogue per tile: top-3 merge butterfly + ballot argmax ----
    const unsigned gsh = (unsigned)(lane & 48);

    auto epi = [&](const f32x4& acc, int tile) {
#pragma unroll
        for (int i = 0; i < 4; ++i) {
            const float lg = acc[i] + bias_lane;    // cols>=8: 0 + (-3e38)
            float a0 = lg, a1 = NEG_BIG, a2 = NEG_BIG;
#pragma unroll
            for (int m = 1; m <= 4; m <<= 1) {
                const float b0 = __shfl_xor(a0, m);
                const float b1 = __shfl_xor(a1, m);
                const float b2 = __shfl_xor(a2, m);
                const float x  = fminf(a0, b0);
                const float c0 = fmaxf(a0, b0);
                const float y  = fmaxf(a1, b1);
                const float z  = fminf(a1, b1);
                const float c1 = fmaxf(x, y);
                const float c2 = fmaxf(fminf(x, y), fmaxf(z, fmaxf(a2, b2)));
                a0 = c0; a1 = c1; a2 = c2;
            }
            // argmax via ballot; exact lax.top_k tie-break (lower index wins)
            const unsigned long long m0 = __ballot(lg == a0);
            const unsigned long long m1 = __ballot(lg == a1);
            const unsigned mk0 = (unsigned)(m0 >> gsh) & 0xFFu;
            const unsigned mk1 = (unsigned)(m1 >> gsh) & 0xFFu;
            const int i0 = __builtin_ctz(mk0);
            const unsigned rest = mk0 & (mk0 - 1);
            const int i1 = (a1 == a0) ? __builtin_ctz(rest | 0x100u)
                                      : __builtin_ctz(mk1 | 0x100u);

            const bool amb = (a0 - a1 < TAU) || (a1 - a2 < TAU);
            const float ex = expf(a1 - a0);        // <= 1
            const float w1 = ex / (1.f + ex);
            const float w0 = 1.f - w1;

            if (col == 0) {
                const size_t t = (size_t)(tile * 16 + (lane >> 4) * 4 + i);
                *reinterpret_cast<float2*>(&out[2 * t]) =
                    make_float2((float)i0, (float)i1);
                *reinterpret_cast<float2*>(&out[2 * (size_t)B_TOKENS + 2 * t]) =
                    make_float2(w0, w1);
                flags[t] = amb ? 1 : 0;            // always written
            }
        }
    };
    epi(acc0, tile0);
    epi(acc1, tile0 + 1);
}

// One wave per 64 consecutive tokens; early-exit when no flags set. (R9-proven.)
__global__ __launch_bounds__(256) void router_repair(
    const float* __restrict__ h,
    const float* __restrict__ gw,
    const float* __restrict__ gb,
    float* __restrict__ out,
    const unsigned char* __restrict__ flags)
{
    const int lane = threadIdx.x & 63;
    const int w = (blockIdx.x * blockDim.x + threadIdx.x) >> 6;
    const int t0 = w * 64;
    if (t0 >= B_TOKENS) return;

    const unsigned char f = flags[t0 + lane];
    unsigned long long mask = __ballot(f != 0);
    if (mask == 0ull) return;

    float wf[NE][3][4];
#pragma unroll
    for (int e = 0; e < NE; ++e)
#pragma unroll
        for (int g = 0; g < 3; ++g) {
            const float4 vv = *reinterpret_cast<const float4*>(
                &gw[e * DM + g * 256 + lane * 4]);
            wf[e][g][0] = vv.x; wf[e][g][1] = vv.y;
            wf[e][g][2] = vv.z; wf[e][g][3] = vv.w;
        }
    double biasd[NE];
#pragma unroll
    for (int e = 0; e < NE; ++e) biasd[e] = (double)gb[e];

    const bool hi32 = (lane & 32) != 0;
    const bool hi16 = (lane & 16) != 0;
    const bool hi8  = (lane & 8)  != 0;

    while (mask) {
        const int p = __ffsll((unsigned long long)mask) - 1;
        mask &= (mask - 1);
        const int t = t0 + p;

        const float* hr = h + (size_t)t * DM;
        float4 buf[3];
#pragma unroll
        for (int g = 0; g < 3; ++g)
            buf[g] = *reinterpret_cast<const float4*>(&hr[g * 256 + lane * 4]);

        double acc[NE] = {0, 0, 0, 0, 0, 0, 0, 0};
#pragma unroll
        for (int g = 0; g < 3; ++g) {
            const float* bp = reinterpret_cast<const float*>(&buf[g]);
#pragma unroll
            for (int j = 0; j < 4; ++j) {
                const double hd = (double)bp[j];
#pragma unroll
                for (int e = 0; e < NE; ++e)
                    acc[e] = fma(hd, (double)wf[e][g][j], acc[e]);
            }
        }
        double d4[4];
#pragma unroll
        for (int j = 0; j < 4; ++j) {
            const double give = hi32 ? acc[j] : acc[4 + j];
            const double keep = hi32 ? acc[4 + j] : acc[j];
            d4[j] = keep + __shfl_xor(give, 32);
        }
        double d2[2];
#pragma unroll
        for (int j = 0; j < 2; ++j) {
            const double give = hi16 ? d4[j] : d4[2 + j];
            const double keep = hi16 ? d4[2 + j] : d4[j];
            d2[j] = keep + __shfl_xor(give, 16);
        }
        const double give = hi8 ? d2[0] : d2[1];
        const double keep = hi8 ? d2[1] : d2[0];
        double dv = keep + __shfl_xor(give, 8);
        dv += __shfl_xor(dv, 4);
        dv += __shfl_xor(dv, 2);
        dv += __shfl_xor(dv, 1);

        double dlg[NE];
#pragma unroll
        for (int e = 0; e < NE; ++e)
            dlg[e] = __shfl(dv, (e << 3) | (lane & 7)) + biasd[e];

        int i0 = 0; double dv0 = dlg[0];
#pragma unroll
        for (int e = 1; e < NE; ++e)
            if (dlg[e] > dv0) { dv0 = dlg[e]; i0 = e; }
        int i1 = (i0 == 0) ? 1 : 0; double dv1 = dlg[i1];
#pragma unroll
        for (int e = 0; e < NE; ++e)
            if (e != i0 && dlg[e] > dv1) { dv1 = dlg[e]; i1 = e; }

        const float ex = expf((float)(dv1 - dv0));
        const float w1 = ex / (1.0f + ex);
        const float w0 = 1.0f - w1;

        if (lane == 0) {
            *reinterpret_cast<float2*>(&out[2 * (size_t)t]) =
                make_float2((float)i0, (float)i1);
            *reinterpret_cast<float2*>(
                &out[2 * (size_t)B_TOKENS + 2 * (size_t)t]) =
                make_float2(w0, w1);
        }
    }
}

extern "C" void kernel_launch(void* const* d_in, const int* in_sizes, int n_in,
                              void* d_out, int out_size, void* d_ws, size_t ws_size,
                              hipStream_t stream) {
    const float* h  = (const float*)d_in[0];
    const float* gw = (const float*)d_in[1];
    const float* gb = (const float*)d_in[2];
    float* out = (float*)d_out;
    unsigned char* flags = (unsigned char*)d_ws;   // B_TOKENS bytes

    router_main<<<dim3(1024), dim3(256), 0, stream>>>(h, gw, gb, out, flags);
    router_repair<<<dim3(512), dim3(256), 0, stream>>>(h, gw, gb, out, flags);
}

// Round 15
// 86.298 us; speedup vs baseline: 1.3805x; 1.0084x over previous
//
#include <hip/hip_runtime.h>
#include <hip/hip_bf16.h>

// TopicRouter: logits = h @ gate_w^T + gate_b ; top-2 ; softmax over top-2.
// Outputs flat in d_out (float32): [0, 2B)   = topk idx as floats
//                                  [2B, 4B)  = softmax weights
//
// R15 = R14 (MFMA hi/lo 3-product, two tiles/wave; 87.0 us) + K-PERMUTED
// FULLY-COALESCED LOADS:
//  * R14 diagnosis: doubling in-flight loads was null (+2%) -> not latency.
//    The A-fragment layout made each load instr touch 32 half-used 64B
//    granules (16B of every 32B, kg*32B offsets) -> 2x granule tax on the
//    whole 402 MB stream.
//  * Fix via the k-permutation freedom (perm applied to BOTH A and B leaves
//    C invariant): lane kg's 8 elements = logical k {kg*4..+3, 16+kg*4..+3}.
//    Load p now reads row-offset kg*16B (contiguous 64B across kg), q at
//    +64B. Every load = 16 fully-used granules. B re-permuted at LDS build:
//    phys(kk) = ((kk&15)>>2)*8 + (kk&3) + ((kk&16)?4:0). Nothing else moves.
//  * Math unchanged: mfma_f32_16x16x32_bf16, hi*hi + hi*lo + lo*hi (exact
//    bf16 products in f32; dropped lo*lo ~2e-5 << TAU=2.5e-4); flag + f64
//    repair kernel (R9-proven) guarantees exact top-2 ranking.
//  * C layout (m89-verified): col = lane&15, row = (lane>>4)*4 + reg.

#define B_TOKENS 131072
#define DM 768
#define NE 8
#define TAU 2.5e-4f
#define NEG_BIG -3.0e38f

typedef __attribute__((ext_vector_type(8))) short bf16x8;
typedef __attribute__((ext_vector_type(4))) float f32x4;

__device__ __forceinline__ unsigned short f32_to_bf16(float f) {
    __hip_bfloat16 b = __float2bfloat16(f);
    return *reinterpret_cast<unsigned short*>(&b);
}
__device__ __forceinline__ float bf16_to_f32(unsigned short u) {
    return __uint_as_float((unsigned)u << 16);
}

__global__ __launch_bounds__(256) void router_main(
    const float* __restrict__ h,     // [B, 768]
    const float* __restrict__ gw,    // [8, 768]
    const float* __restrict__ gb,    // [8]
    float* __restrict__ out,         // [2B idx floats][2B weight floats]
    unsigned char* __restrict__ flags)
{
    // [kstep 24][col 8: 72 ushorts = 32 hi + 32 lo + 8 pad] + 8 zero stub
    __shared__ __align__(16) unsigned short w_lds[24 * 576 + 8];

    const int tid  = threadIdx.x;
    const int lane = tid & 63;
    const int wv   = tid >> 6;
    const int col  = lane & 15;
    const int kg   = lane >> 4;

    // ---- build B hi/lo in LDS, k-permuted to match coalesced A loads ----
    for (int idx = tid; idx < NE * DM; idx += 256) {
        const int e = idx / DM, k = idx - e * DM;
        const float w = gw[idx];
        const unsigned short hb = f32_to_bf16(w);
        const unsigned short lb = f32_to_bf16(w - bf16_to_f32(hb));
        const int ks = k >> 5, kk = k & 31;
        // physical slot within the 32-run for logical kk:
        const int phys = (((kk & 15) >> 2) << 3) + (kk & 3) + ((kk & 16) ? 4 : 0);
        w_lds[ks * 576 + e * 72 + phys]      = hb;
        w_lds[ks * 576 + e * 72 + 32 + phys] = lb;
    }
    if (tid < 8) w_lds[24 * 576 + tid] = 0;

    const float bias_lane = (col < 8) ? gb[col] : NEG_BIG;
    __syncthreads();

    // ---- per-wave: two adjacent 16-token tiles ----
    const int tile0 = (blockIdx.x * 4 + wv) * 2;     // [0, 8192) step 2
    // lane's base: row (tile*16 + col), k-offset kg*4 floats (16B)
    const float* arow0 = h + (size_t)(tile0 * 16 + col) * DM + kg * 4;
    const float* arow1 = arow0 + (size_t)16 * DM;

    const unsigned short* bptr =
        (col < 8) ? &w_lds[col * 72 + kg * 8] : &w_lds[24 * 576];
    const int bstep = (col < 8) ? 576 : 0;
    const int bloff = (col < 8) ? 32 : 0;

    f32x4 acc0 = {0.f, 0.f, 0.f, 0.f};
    f32x4 acc1 = {0.f, 0.f, 0.f, 0.f};

#pragma unroll 2
    for (int ks = 0; ks < 24; ++ks) {
        // fully-coalesced: p at +0 (kg*16B within 64B), q at +64B
        const float4 p0 = *reinterpret_cast<const float4*>(arow0 + ks * 32);
        const float4 q0 = *reinterpret_cast<const float4*>(arow0 + ks * 32 + 16);
        const float4 p1 = *reinterpret_cast<const float4*>(arow1 + ks * 32);
        const float4 q1 = *reinterpret_cast<const float4*>(arow1 + ks * 32 + 16);

        const bf16x8 bhi = *reinterpret_cast<const bf16x8*>(bptr + ks * bstep);
        const bf16x8 blo = *reinterpret_cast<const bf16x8*>(bptr + ks * bstep + bloff);

        bf16x8 ahi0, alo0, ahi1, alo1;
        {
            const float f0[8] = {p0.x, p0.y, p0.z, p0.w, q0.x, q0.y, q0.z, q0.w};
            const float f1[8] = {p1.x, p1.y, p1.z, p1.w, q1.x, q1.y, q1.z, q1.w};
#pragma unroll
            for (int j = 0; j < 8; ++j) {
                unsigned short hb = f32_to_bf16(f0[j]);
                ahi0[j] = (short)hb;
                alo0[j] = (short)f32_to_bf16(f0[j] - bf16_to_f32(hb));
                hb = f32_to_bf16(f1[j]);
                ahi1[j] = (short)hb;
                alo1[j] = (short)f32_to_bf16(f1[j] - bf16_to_f32(hb));
            }
        }
        acc0 = __builtin_amdgcn_mfma_f32_16x16x32_bf16(ahi0, bhi, acc0, 0, 0, 0);
        acc0 = __builtin_amdgcn_mfma_f32_16x16x32_bf16(ahi0, blo, acc0, 0, 0, 0);
        acc0 = __builtin_amdgcn_mfma_f32_16x16x32_bf16(alo0, bhi, acc0, 0, 0, 0);
        acc1 = __builtin_amdgcn_mfma_f32_16x16x32_bf16(ahi1, bhi, acc1, 0, 0, 0);
        acc1 = __builtin_amdgcn_mfma_f32_16x16x32_bf16(ahi1, blo, acc1, 0, 0, 0);
        acc1 = __builtin_amdgcn_mfma_f32_16x16x32_bf16(alo1, bhi, acc1, 0, 0, 0);
    }

    // ---- epilogue per tile: top-3 merge butterfly + ballot argmax ----
    const unsigned gsh = (unsigned)(lane & 48);

    auto epi = [&](const f32x4& acc, int tile) {
#pragma unroll
        for (int i = 0; i < 4; ++i) {
            const float lg = acc[i] + bias_lane;    // cols>=8: 0 + (-3e38)
            float a0 = lg, a1 = NEG_BIG, a2 = NEG_BIG;
#pragma unroll
            for (int m = 1; m <= 4; m <<= 1) {
                const float b0 = __shfl_xor(a0, m);
                const float b1 = __shfl_xor(a1, m);
                const float b2 = __shfl_xor(a2, m);
                const float x  = fminf(a0, b0);
                const float c0 = fmaxf(a0, b0);
                const float y  = fmaxf(a1, b1);
                const float z  = fminf(a1, b1);
                const float c1 = fmaxf(x, y);
                const float c2 = fmaxf(fminf(x, y), fmaxf(z, fmaxf(a2, b2)));
                a0 = c0; a1 = c1; a2 = c2;
            }
            // argmax via ballot; exact lax.top_k tie-break (lower index wins)
            const unsigned long long m0 = __ballot(lg == a0);
            const unsigned long long m1 = __ballot(lg == a1);
            const unsigned mk0 = (unsigned)(m0 >> gsh) & 0xFFu;
            const unsigned mk1 = (unsigned)(m1 >> gsh) & 0xFFu;
            const int i0 = __builtin_ctz(mk0);
            const unsigned rest = mk0 & (mk0 - 1);
            const int i1 = (a1 == a0) ? __builtin_ctz(rest | 0x100u)
                                      : __builtin_ctz(mk1 | 0x100u);

            const bool amb = (a0 - a1 < TAU) || (a1 - a2 < TAU);
            const float ex = expf(a1 - a0);        // <= 1
            const float w1 = ex / (1.f + ex);
            const float w0 = 1.f - w1;

            if (col == 0) {
                const size_t t = (size_t)(tile * 16 + (lane >> 4) * 4 + i);
                *reinterpret_cast<float2*>(&out[2 * t]) =
                    make_float2((float)i0, (float)i1);
                *reinterpret_cast<float2*>(&out[2 * (size_t)B_TOKENS + 2 * t]) =
                    make_float2(w0, w1);
                flags[t] = amb ? 1 : 0;            // always written
            }
        }
    };
    epi(acc0, tile0);
    epi(acc1, tile0 + 1);
}

// One wave per 64 consecutive tokens; early-exit when no flags set. (R9-proven.)
__global__ __launch_bounds__(256) void router_repair(
    const float* __restrict__ h,
    const float* __restrict__ gw,
    const float* __restrict__ gb,
    float* __restrict__ out,
    const unsigned char* __restrict__ flags)
{
    const int lane = threadIdx.x & 63;
    const int w = (blockIdx.x * blockDim.x + threadIdx.x) >> 6;
    const int t0 = w * 64;
    if (t0 >= B_TOKENS) return;

    const unsigned char f = flags[t0 + lane];
    unsigned long long mask = __ballot(f != 0);
    if (mask == 0ull) return;

    float wf[NE][3][4];
#pragma unroll
    for (int e = 0; e < NE; ++e)
#pragma unroll
        for (int g = 0; g < 3; ++g) {
            const float4 vv = *reinterpret_cast<const float4*>(
                &gw[e * DM + g * 256 + lane * 4]);
            wf[e][g][0] = vv.x; wf[e][g][1] = vv.y;
            wf[e][g][2] = vv.z; wf[e][g][3] = vv.w;
        }
    double biasd[NE];
#pragma unroll
    for (int e = 0; e < NE; ++e) biasd[e] = (double)gb[e];

    const bool hi32 = (lane & 32) != 0;
    const bool hi16 = (lane & 16) != 0;
    const bool hi8  = (lane & 8)  != 0;

    while (mask) {
        const int p = __ffsll((unsigned long long)mask) - 1;
        mask &= (mask - 1);
        const int t = t0 + p;

        const float* hr = h + (size_t)t * DM;
        float4 buf[3];
#pragma unroll
        for (int g = 0; g < 3; ++g)
            buf[g] = *reinterpret_cast<const float4*>(&hr[g * 256 + lane * 4]);

        double acc[NE] = {0, 0, 0, 0, 0, 0, 0, 0};
#pragma unroll
        for (int g = 0; g < 3; ++g) {
            const float* bp = reinterpret_cast<const float*>(&buf[g]);
#pragma unroll
            for (int j = 0; j < 4; ++j) {
                const double hd = (double)bp[j];
#pragma unroll
                for (int e = 0; e < NE; ++e)
                    acc[e] = fma(hd, (double)wf[e][g][j], acc[e]);
            }
        }
        double d4[4];
#pragma unroll
        for (int j = 0; j < 4; ++j) {
            const double give = hi32 ? acc[j] : acc[4 + j];
            const double keep = hi32 ? acc[4 + j] : acc[j];
            d4[j] = keep + __shfl_xor(give, 32);
        }
        double d2[2];
#pragma unroll
        for (int j = 0; j < 2; ++j) {
            const double give = hi16 ? d4[j] : d4[2 + j];
            const double keep = hi16 ? d4[2 + j] : d4[j];
            d2[j] = keep + __shfl_xor(give, 16);
        }
        const double give = hi8 ? d2[0] : d2[1];
        const double keep = hi8 ? d2[1] : d2[0];
        double dv = keep + __shfl_xor(give, 8);
        dv += __shfl_xor(dv, 4);
        dv += __shfl_xor(dv, 2);
        dv += __shfl_xor(dv, 1);

        double dlg[NE];
#pragma unroll
        for (int e = 0; e < NE; ++e)
            dlg[e] = __shfl(dv, (e << 3) | (lane & 7)) + biasd[e];

        int i0 = 0; double dv0 = dlg[0];
#pragma unroll
        for (int e = 1; e < NE; ++e)
            if (dlg[e] > dv0) { dv0 = dlg[e]; i0 = e; }
        int i1 = (i0 == 0) ? 1 : 0; double dv1 = dlg[i1];
#pragma unroll
        for (int e = 0; e < NE; ++e)
            if (e != i0 && dlg[e] > dv1) { dv1 = dlg[e]; i1 = e; }

        const float ex = expf((float)(dv1 - dv0));
        const float w1 = ex / (1.0f + ex);
        const float w0 = 1.0f - w1;

        if (lane == 0) {
            *reinterpret_cast<float2*>(&out[2 * (size_t)t]) =
                make_float2((float)i0, (float)i1);
            *reinterpret_cast<float2*>(
                &out[2 * (size_t)B_TOKENS + 2 * (size_t)t]) =
                make_float2(w0, w1);
        }
    }
}

extern "C" void kernel_launch(void* const* d_in, const int* in_sizes, int n_in,
                              void* d_out, int out_size, void* d_ws, size_t ws_size,
                              hipStream_t stream) {
    const float* h  = (const float*)d_in[0];
    const float* gw = (const float*)d_in[1];
    const float* gb = (const float*)d_in[2];
    float* out = (float*)d_out;
    unsigned char* flags = (unsigned char*)d_ws;   // B_TOKENS bytes

    router_main<<<dim3(1024), dim3(256), 0, stream>>>(h, gw, gb, out, flags);
    router_repair<<<dim3(512), dim3(256), 0, stream>>>(h, gw, gb, out, flags);
}